// Round 1
// baseline (614.219 us; speedup 1.0000x reference)
//
#include <hip/hip_runtime.h>
#include <hip/hip_bf16.h>
#include <stdint.h>

#define NTOK 8192          // B*L = 8*1024
#define DM   1024

typedef __bf16 bf16x8 __attribute__((ext_vector_type(8)));
typedef float  f32x4  __attribute__((ext_vector_type(4)));

__device__ __forceinline__ unsigned short f2bf(float f) {
  union { float f; unsigned u; } v; v.f = f;
  unsigned r = v.u + 0x7FFFu + ((v.u >> 16) & 1u);   // round-to-nearest-even
  return (unsigned short)(r >> 16);
}

// async global->LDS, 16B per lane; LDS dest = wave-uniform base + lane*16
__device__ __forceinline__ void gld16(const void* g, const void* l) {
  __builtin_amdgcn_global_load_lds(
      (const __attribute__((address_space(1))) uint32_t*)g,
      (__attribute__((address_space(3))) uint32_t*)l, 16, 0, 0);
}

// ---------------- convert x: fp32 [tok][3][1024] -> bf16 [s][tok][1024] ----------------
__global__ void convert_x(const float* __restrict__ x, unsigned short* __restrict__ Xbf) {
  int idx = (blockIdx.x * 256 + threadIdx.x) * 4;
  int s   = idx >> 23;
  int rem = idx & ((1 << 23) - 1);
  int tok = rem >> 10;
  int d   = rem & 1023;
  const float4 v = *(const float4*)&x[((size_t)tok * 3 + s) * 1024 + d];
  ushort4 o;
  o.x = f2bf(v.x); o.y = f2bf(v.y); o.z = f2bf(v.z); o.w = f2bf(v.w);
  *(ushort4*)&Xbf[idx] = o;
}

// ---------------- W (K x N fp32) -> Wt (N x K bf16), 1024x1024 ----------------
__global__ void transpose_w(const float* __restrict__ W, unsigned short* __restrict__ Wt) {
  __shared__ float t[32][33];
  int tx = threadIdx.x, ty = threadIdx.y;            // block (32,8)
  int bx = blockIdx.x * 32, by = blockIdx.y * 32;
#pragma unroll
  for (int i = 0; i < 32; i += 8)
    t[ty + i][tx] = W[(size_t)(by + ty + i) * 1024 + bx + tx];
  __syncthreads();
#pragma unroll
  for (int i = 0; i < 32; i += 8)
    Wt[(size_t)(bx + ty + i) * 1024 + by + tx] = f2bf(t[tx][ty + i]);  // Wt[n][k]=W[k][n]
}

// ---------------- shared 128x128 GEMM core, A: Mx1024 bf16, Bt: Nx1024 bf16 ----------------
// grid: x = m-block (so A-tile sharers land on the same XCD), y = n-block
// LDS tiles XOR-swizzled by (row>>1)&3 -> 8 bank-groups per quad -> 2-way (free)
__device__ __forceinline__ void gemm128_core(
    const unsigned short* __restrict__ A, const unsigned short* __restrict__ Bt,
    unsigned short* lA, unsigned short* lB, f32x4 acc[4][4])
{
  int tid  = threadIdx.x;
  int wave = tid >> 6, lane = tid & 63, quad = lane >> 4, l16 = lane & 15;
  int m0 = blockIdx.x * 128, n0 = blockIdx.y * 128;
  int r0 = tid >> 2;
  int kc = (((tid & 3) ^ ((tid >> 3) & 3)) * 8);     // XOR source swizzle, key (r0>>1)&3
  const unsigned short* Ag = A  + (size_t)(m0 + r0) * 1024 + kc;
  const unsigned short* Bg = Bt + (size_t)(n0 + r0) * 1024 + kc;
  int wm = (wave >> 1) * 64, wn = (wave & 1) * 64;
  int fsw = (l16 >> 1) & 3;                          // fragment-read swizzle key

  for (int k0 = 0; k0 < 1024; k0 += 32) {
    gld16(Ag + k0,             lA + wave * 512);
    gld16(Ag + k0 + 64 * 1024, lA + 2048 + wave * 512);
    gld16(Bg + k0,             lB + wave * 512);
    gld16(Bg + k0 + 64 * 1024, lB + 2048 + wave * 512);
    __syncthreads();
    bf16x8 af[4], bfr[4];
    int fo = ((quad ^ fsw) * 8);
#pragma unroll
    for (int i = 0; i < 4; i++) {
      af[i]  = *(const bf16x8*)&lA[(wm + i * 16 + l16) * 32 + fo];
      bfr[i] = *(const bf16x8*)&lB[(wn + i * 16 + l16) * 32 + fo];
    }
#pragma unroll
    for (int mi = 0; mi < 4; mi++)
#pragma unroll
      for (int ni = 0; ni < 4; ni++)
        acc[mi][ni] = __builtin_amdgcn_mfma_f32_16x16x32_bf16(af[mi], bfr[ni], acc[mi][ni], 0, 0, 0);
    __syncthreads();
  }
}

// ---------------- 9 projection GEMMs: P[s*3+w] = Xbf[s] @ W[w] + bias[w], bf16 out ----------------
// w==2 (V) is stored TRANSPOSED into its P slice: [(b*16+h)][d][l] (fused transpose_v)
__global__ __launch_bounds__(256, 2) void gemm_proj(
    const unsigned short* __restrict__ Xbf, const unsigned short* __restrict__ Wt,
    unsigned short* __restrict__ P,
    const float* __restrict__ bq, const float* __restrict__ bk, const float* __restrict__ bv)
{
  __shared__ alignas(16) unsigned short lA[128 * 32];
  __shared__ alignas(16) unsigned short lB[128 * 32];
  int z = blockIdx.z, s = z / 3, w = z - s * 3;
  const float* bias = (w == 0) ? bq : (w == 1) ? bk : bv;
  f32x4 acc[4][4];
#pragma unroll
  for (int i = 0; i < 4; i++)
#pragma unroll
    for (int j = 0; j < 4; j++) acc[i][j] = (f32x4){0.f, 0.f, 0.f, 0.f};
  gemm128_core(Xbf + (size_t)s * NTOK * 1024, Wt + (size_t)w * 1024 * 1024, lA, lB, acc);

  int tid = threadIdx.x, wave = tid >> 6, lane = tid & 63, quad = lane >> 4, l16 = lane & 15;
  int m0 = blockIdx.x * 128 + (wave >> 1) * 64;
  int n0 = blockIdx.y * 128 + (wave & 1) * 64;
  unsigned short* C = P + (size_t)z * NTOK * 1024;
  if (w == 2) {
    // fused V transpose: C-layout gives each lane 4 consecutive rows (= consecutive l)
    // at a fixed col (= h*64+d)  ->  contiguous ushort4 store into Vt[(b,h)][d][l]
#pragma unroll
    for (int mi = 0; mi < 4; mi++) {
      int row0 = m0 + mi * 16 + quad * 4;
      int b = row0 >> 10, l0 = row0 & 1023;
#pragma unroll
      for (int ni = 0; ni < 4; ni++) {
        int col = n0 + ni * 16 + l16;
        float bcol = bias[col];
        int hh = col >> 6, d = col & 63;
        ushort4 o4;
        o4.x = f2bf(acc[mi][ni][0] + bcol);
        o4.y = f2bf(acc[mi][ni][1] + bcol);
        o4.z = f2bf(acc[mi][ni][2] + bcol);
        o4.w = f2bf(acc[mi][ni][3] + bcol);
        *(ushort4*)&C[(size_t)(b * 16 + hh) * 65536 + (size_t)d * 1024 + l0] = o4;
      }
    }
  } else {
#pragma unroll
    for (int mi = 0; mi < 4; mi++)
#pragma unroll
      for (int ni = 0; ni < 4; ni++) {
        int col = n0 + ni * 16 + l16;
        float bcol = bias[col];
#pragma unroll
        for (int r = 0; r < 4; r++) {
          int row = m0 + mi * 16 + quad * 4 + r;
          C[(size_t)row * 1024 + col] = f2bf(acc[mi][ni][r] + bcol);
        }
      }
  }
}

// ---------------- fused dual attention v5: grid x=bh (K/V sharers on same XCD), y=q-block ----------------
__global__ __launch_bounds__(256, 4) void attn(
    const unsigned short* __restrict__ P, unsigned short* __restrict__ Oa)
{
  __shared__ alignas(16) unsigned short lK1[64 * 64];   // [key][8 x 16B chunks, XOR-swizzled]
  __shared__ alignas(16) unsigned short lK2[64 * 64];
  __shared__ alignas(16) unsigned short lV [64 * 64];   // [d][8 chunks of keys, XOR-swizzled]
  __shared__ alignas(16) unsigned short pls[4][32 * 40];// per-wave P relayout, 80B rows
  int o  = blockIdx.z;
  int As = (o == 0) ? 1 : 0;          // first (q,k) source stream
  int Bs = (o == 2) ? 1 : 2;          // second (q,k) source stream
  int b = blockIdx.x >> 4, h = blockIdx.x & 15;
  int tid = threadIdx.x, wave = tid >> 6, lane = tid & 63, quad = lane >> 4, l16 = lane & 15;
  int q0 = blockIdx.y * 128 + wave * 32;
  size_t bh_off = (size_t)b * 1024 * 1024 + h * 64;
  const unsigned short* Q1 = P + (size_t)(As * 3 + 0) * NTOK * 1024 + bh_off;
  const unsigned short* K1 = P + (size_t)(As * 3 + 1) * NTOK * 1024 + bh_off;
  const unsigned short* Q2 = P + (size_t)(Bs * 3 + 0) * NTOK * 1024 + bh_off;
  const unsigned short* K2 = P + (size_t)(Bs * 3 + 1) * NTOK * 1024 + bh_off;
  // V lives transposed inside the (o,w==2) P slice: [(b*16+h)][d][l]
  const unsigned short* V  = P + (size_t)(o * 3 + 2) * NTOK * 1024
                               + (size_t)(b * 16 + h) * 65536;
  unsigned short* myp = pls[wave];

  bf16x8 q1f[2][2], q2f[2][2];
#pragma unroll
  for (int qt = 0; qt < 2; qt++)
#pragma unroll
    for (int c = 0; c < 2; c++) {
      q1f[qt][c] = *(const bf16x8*)&Q1[(size_t)(q0 + qt * 16 + l16) * 1024 + c * 32 + quad * 8];
      q2f[qt][c] = *(const bf16x8*)&Q2[(size_t)(q0 + qt * 16 + l16) * 1024 + c * 32 + quad * 8];
    }
  bf16x8 ones;
#pragma unroll
  for (int j = 0; j < 8; j++) ones[j] = (__bf16)1.0f;

  // staging: lane covers row (wave*16 + lane/8), swizzled 16B chunk (lane%8)^(row%8)
  int r8 = lane >> 3;
  int cs = ((lane & 7) ^ r8) * 8;                      // XOR source swizzle
  int srow = wave * 16 + r8;
  const unsigned short* K1s = K1 + (size_t)srow * 1024 + cs;
  const unsigned short* K2s = K2 + (size_t)srow * 1024 + cs;
  const unsigned short* Vs  = V  + (size_t)srow * 1024 + cs;
  int fsw = (l16 & 7);                                 // fragment-read swizzle key

  f32x4 oacc[2][4];
#pragma unroll
  for (int qt = 0; qt < 2; qt++)
#pragma unroll
    for (int dt = 0; dt < 4; dt++) oacc[qt][dt] = (f32x4){0.f, 0.f, 0.f, 0.f};
  f32x4 lsum[2];
  lsum[0] = (f32x4){0.f, 0.f, 0.f, 0.f};
  lsum[1] = (f32x4){0.f, 0.f, 0.f, 0.f};

  const float SC = 0.09016844136867f;  // (1/sqrt(64))*0.5*log2(e)

  for (int k0 = 0; k0 < 1024; k0 += 64) {
#pragma unroll
    for (int half = 0; half < 2; half++) {
      size_t krow = (size_t)(k0 + half * 8) * 1024;
      gld16(K1s + krow,                 lK1 + (wave * 16 + half * 8) * 64);
      gld16(K2s + krow,                 lK2 + (wave * 16 + half * 8) * 64);
      gld16(Vs + k0 + half * 8 * 1024,  lV  + (wave * 16 + half * 8) * 64);
    }
    __syncthreads();

#pragma unroll
    for (int kc = 0; kc < 2; kc++) {              // 32-key halves of the 64-key stage
      f32x4 sacc[2][2];
      sacc[0][0] = (f32x4){0.f, 0.f, 0.f, 0.f};
      sacc[0][1] = (f32x4){0.f, 0.f, 0.f, 0.f};
      sacc[1][0] = (f32x4){0.f, 0.f, 0.f, 0.f};
      sacc[1][1] = (f32x4){0.f, 0.f, 0.f, 0.f};
      __builtin_amdgcn_s_setprio(1);              // T5: favor the QK MFMA cluster
#pragma unroll
      for (int kt = 0; kt < 2; kt++) {
        int krow = (kc * 32 + kt * 16 + l16) * 64;
        bf16x8 k1a = *(const bf16x8*)&lK1[krow + ((quad ^ fsw) * 8)];
        bf16x8 k1b = *(const bf16x8*)&lK1[krow + (((quad + 4) ^ fsw) * 8)];
        bf16x8 k2a = *(const bf16x8*)&lK2[krow + ((quad ^ fsw) * 8)];
        bf16x8 k2b = *(const bf16x8*)&lK2[krow + (((quad + 4) ^ fsw) * 8)];
#pragma unroll
        for (int qt = 0; qt < 2; qt++) {
          sacc[qt][kt] = __builtin_amdgcn_mfma_f32_16x16x32_bf16(q1f[qt][0], k1a, sacc[qt][kt], 0, 0, 0);
          sacc[qt][kt] = __builtin_amdgcn_mfma_f32_16x16x32_bf16(q1f[qt][1], k1b, sacc[qt][kt], 0, 0, 0);
          sacc[qt][kt] = __builtin_amdgcn_mfma_f32_16x16x32_bf16(q2f[qt][0], k2a, sacc[qt][kt], 0, 0, 0);
          sacc[qt][kt] = __builtin_amdgcn_mfma_f32_16x16x32_bf16(q2f[qt][1], k2b, sacc[qt][kt], 0, 0, 0);
        }
      }
      __builtin_amdgcn_s_setprio(0);
      // exp2 -> bf16 pair-pack (round-half-up) -> padded per-wave LDS, read back A-layout
#pragma unroll
      for (int qt = 0; qt < 2; qt++)
#pragma unroll
        for (int kt = 0; kt < 2; kt++)
#pragma unroll
          for (int r2 = 0; r2 < 2; r2++) {
            union { float f; unsigned u; } e0, e1;
            e0.f = __builtin_amdgcn_exp2f(sacc[qt][kt][r2 * 2]     * SC);
            e1.f = __builtin_amdgcn_exp2f(sacc[qt][kt][r2 * 2 + 1] * SC);
            unsigned pk = __builtin_amdgcn_perm(e1.u + 0x8000u, e0.u + 0x8000u, 0x07060302u);
            int row = qt * 16 + quad * 4 + r2 * 2;
            myp[row * 40 + kt * 16 + l16]       = (unsigned short)pk;
            myp[(row + 1) * 40 + kt * 16 + l16] = (unsigned short)(pk >> 16);
          }
      bf16x8 pa0 = *(const bf16x8*)&myp[l16 * 40 + quad * 8];
      bf16x8 pa1 = *(const bf16x8*)&myp[(16 + l16) * 40 + quad * 8];
      __builtin_amdgcn_s_setprio(1);              // T5: favor lsum+PV MFMA cluster
      lsum[0] = __builtin_amdgcn_mfma_f32_16x16x32_bf16(pa0, ones, lsum[0], 0, 0, 0);
      lsum[1] = __builtin_amdgcn_mfma_f32_16x16x32_bf16(pa1, ones, lsum[1], 0, 0, 0);
#pragma unroll
      for (int dt = 0; dt < 4; dt++) {
        bf16x8 vf = *(const bf16x8*)&lV[(dt * 16 + l16) * 64 + (((kc * 4 + quad) ^ fsw) * 8)];
        oacc[0][dt] = __builtin_amdgcn_mfma_f32_16x16x32_bf16(pa0, vf, oacc[0][dt], 0, 0, 0);
        oacc[1][dt] = __builtin_amdgcn_mfma_f32_16x16x32_bf16(pa1, vf, oacc[1][dt], 0, 0, 0);
      }
      __builtin_amdgcn_s_setprio(0);
    }
    __syncthreads();
  }

  unsigned short* Od = Oa + (size_t)o * NTOK * 1024 + bh_off;
#pragma unroll
  for (int qt = 0; qt < 2; qt++) {
    f32x4 inv;
#pragma unroll
    for (int r = 0; r < 4; r++) inv[r] = 1.0f / lsum[qt][r];
#pragma unroll
    for (int dt = 0; dt < 4; dt++)
#pragma unroll
      for (int r = 0; r < 4; r++) {
        float val = oacc[qt][dt][r] * inv[r];
        Od[(size_t)(q0 + qt * 16 + quad * 4 + r) * 1024 + dt * 16 + l16] = f2bf(val);
      }
  }
}

// ---------------- output GEMM: d_out[tok][s][:] = Oa[s] @ Wo + bo (fp32) ----------------
__global__ __launch_bounds__(256, 2) void gemm_out(
    const unsigned short* __restrict__ Oattn, const unsigned short* __restrict__ WtO,
    float* __restrict__ out, const float* __restrict__ bo)
{
  __shared__ alignas(16) unsigned short lA[128 * 32];
  __shared__ alignas(16) unsigned short lB[128 * 32];
  int s = blockIdx.z;
  f32x4 acc[4][4];
#pragma unroll
  for (int i = 0; i < 4; i++)
#pragma unroll
    for (int j = 0; j < 4; j++) acc[i][j] = (f32x4){0.f, 0.f, 0.f, 0.f};
  gemm128_core(Oattn + (size_t)s * NTOK * 1024, WtO, lA, lB, acc);

  int tid = threadIdx.x, wave = tid >> 6, lane = tid & 63, quad = lane >> 4, l16 = lane & 15;
  int m0 = blockIdx.x * 128 + (wave >> 1) * 64;
  int n0 = blockIdx.y * 128 + (wave & 1) * 64;
#pragma unroll
  for (int mi = 0; mi < 4; mi++)
#pragma unroll
    for (int ni = 0; ni < 4; ni++) {
      int col = n0 + ni * 16 + l16;
      float bcol = bo[col];
#pragma unroll
      for (int r = 0; r < 4; r++) {
        int row = m0 + mi * 16 + quad * 4 + r;
        out[(size_t)row * 3072 + s * 1024 + col] = acc[mi][ni][r] + bcol;
      }
    }
}

extern "C" void kernel_launch(void* const* d_in, const int* in_sizes, int n_in,
                              void* d_out, int out_size, void* d_ws, size_t ws_size,
                              hipStream_t stream) {
  (void)in_sizes; (void)n_in; (void)out_size; (void)ws_size;
  const float* x  = (const float*)d_in[0];
  const float* Wq = (const float*)d_in[1];
  const float* bq = (const float*)d_in[2];
  const float* Wk = (const float*)d_in[3];
  const float* bk = (const float*)d_in[4];
  const float* Wv = (const float*)d_in[5];
  const float* bv = (const float*)d_in[6];
  const float* Wo = (const float*)d_in[7];
  const float* bo = (const float*)d_in[8];
  float* out = (float*)d_out;

  char* ws = (char*)d_ws;
  // layout (bytes): Xbf 48MB | Wt 8MB | P 144MB (w==2 slices hold Vt-transposed) | Oa 48MB
  unsigned short* Xbf = (unsigned short*)(ws + 0);
  unsigned short* Wt  = (unsigned short*)(ws + 50331648);
  unsigned short* P   = (unsigned short*)(ws + 58720256);
  unsigned short* Oa  = (unsigned short*)(ws + 209715200);

  convert_x<<<24576, 256, 0, stream>>>(x, Xbf);
  dim3 tb(32, 8), tg(32, 32);
  transpose_w<<<tg, tb, 0, stream>>>(Wq, Wt + 0 * 1048576);
  transpose_w<<<tg, tb, 0, stream>>>(Wk, Wt + 1 * 1048576);
  transpose_w<<<tg, tb, 0, stream>>>(Wv, Wt + 2 * 1048576);
  transpose_w<<<tg, tb, 0, stream>>>(Wo, Wt + 3 * 1048576);

  gemm_proj<<<dim3(64, 8, 9), 256, 0, stream>>>(Xbf, Wt, P, bq, bk, bv);
  attn<<<dim3(128, 8, 3), 256, 0, stream>>>(P, Oa);
  gemm_out<<<dim3(64, 8, 3), 256, 0, stream>>>(Oa, Wt + 3 * 1048576, out, bo);
}

// Round 2
// 613.497 us; speedup vs baseline: 1.0012x; 1.0012x over previous
//
#include <hip/hip_runtime.h>
#include <hip/hip_bf16.h>
#include <stdint.h>

#define NTOK 8192          // B*L = 8*1024
#define DM   1024

typedef __bf16 bf16x8 __attribute__((ext_vector_type(8)));
typedef float  f32x4  __attribute__((ext_vector_type(4)));

__device__ __forceinline__ unsigned short f2bf(float f) {
  union { float f; unsigned u; } v; v.f = f;
  unsigned r = v.u + 0x7FFFu + ((v.u >> 16) & 1u);   // round-to-nearest-even
  return (unsigned short)(r >> 16);
}

// async global->LDS, 16B per lane; LDS dest = wave-uniform base + lane*16
__device__ __forceinline__ void gld16(const void* g, const void* l) {
  __builtin_amdgcn_global_load_lds(
      (const __attribute__((address_space(1))) uint32_t*)g,
      (__attribute__((address_space(3))) uint32_t*)l, 16, 0, 0);
}

// ---------------- convert x: fp32 [tok][3][1024] -> bf16 [s][tok][1024] ----------------
__global__ void convert_x(const float* __restrict__ x, unsigned short* __restrict__ Xbf) {
  int idx = (blockIdx.x * 256 + threadIdx.x) * 4;
  int s   = idx >> 23;
  int rem = idx & ((1 << 23) - 1);
  int tok = rem >> 10;
  int d   = rem & 1023;
  const float4 v = *(const float4*)&x[((size_t)tok * 3 + s) * 1024 + d];
  ushort4 o;
  o.x = f2bf(v.x); o.y = f2bf(v.y); o.z = f2bf(v.z); o.w = f2bf(v.w);
  *(ushort4*)&Xbf[idx] = o;
}

// ---------------- W (K x N fp32) -> Wt (N x K bf16), 1024x1024 ----------------
__global__ void transpose_w(const float* __restrict__ W, unsigned short* __restrict__ Wt) {
  __shared__ float t[32][33];
  int tx = threadIdx.x, ty = threadIdx.y;            // block (32,8)
  int bx = blockIdx.x * 32, by = blockIdx.y * 32;
#pragma unroll
  for (int i = 0; i < 32; i += 8)
    t[ty + i][tx] = W[(size_t)(by + ty + i) * 1024 + bx + tx];
  __syncthreads();
#pragma unroll
  for (int i = 0; i < 32; i += 8)
    Wt[(size_t)(bx + ty + i) * 1024 + by + tx] = f2bf(t[tx][ty + i]);  // Wt[n][k]=W[k][n]
}

// ================= 256x256 8-phase GEMM core (T2+T3+T4+T5) =================
// A: Mx1024 bf16 row-major, Bt: Nx1024 bf16 row-major. 512 thr = 8 waves (2M x 4N).
// Per-wave C: 128x64 = 8mi x 4ni frags. K-tile BK=64, double-buffered.
// LDS 128KB: A slots (buf,half) at (buf*2+half)*8192, B at +32768. Half = 128 rows x 64k.
// Swizzle: phys(row, chunk) holds logical chunk^(row&7)  (chunk = 16B unit of the 128B row).
// Staged via pre-swizzled global source (gld_lds writes linearly); read with XOR'd chunk.
// Schedule per 8-phase iter computing tiles (t,t+1):
//   ph1: rd A0,B0(t) | stage (t+1)B1   ph2: rd A1(t)
//   ph3: rd B1(t)    | stage (t+2)A0,A1   ph4: stage (t+2)B0, vmcnt(6)
//   ph5: rd A0,B0(t+1) | stage (t+2)B1    ph6: rd A1(t+1)
//   ph7: rd B1(t+1)  | stage (t+3)A0,A1   ph8: stage (t+3)B0, vmcnt(6)
// WAR: every slot overwrite issued >=1 barrier after its last read (A slots read ph1-2,
// B slots ph1&3 of their tile). RAW: vmcnt(6) leaves exactly the 3 newest halves in flight.
#define STG_A(tt, d, hf) do { \
  gld16(Ag + (size_t)((hf) * 128) * 1024 + (tt) * 64,      &lds[((d)*2+(hf))*8192 + wave*512]); \
  gld16(Ag + (size_t)((hf) * 128 + 64) * 1024 + (tt) * 64, &lds[((d)*2+(hf))*8192 + wave*512 + 4096]); \
} while (0)
#define STG_B(tt, d, hf) do { \
  gld16(Bg + (size_t)((hf) * 128) * 1024 + (tt) * 64,      &lds[32768 + ((d)*2+(hf))*8192 + wave*512]); \
  gld16(Bg + (size_t)((hf) * 128 + 64) * 1024 + (tt) * 64, &lds[32768 + ((d)*2+(hf))*8192 + wave*512 + 4096]); \
} while (0)
#define RD_AG(g, d) do { \
  const unsigned short* _p = &lds[((d)*2 + wm) * 8192]; \
  _Pragma("unroll") for (int m2 = 0; m2 < 4; ++m2) \
  _Pragma("unroll") for (int ks = 0; ks < 2; ++ks) \
    af[(g)*4 + m2][ks] = *(const bf16x8*)&_p[((g)*4 + m2)*1024 + l16*64 + (((ks*4 + quad) ^ sw8) * 8)]; \
} while (0)
#define RD_BG(g, d) do { \
  const unsigned short* _p = &lds[32768 + ((d)*2 + (wn >> 1)) * 8192 + (wn & 1) * 4096]; \
  _Pragma("unroll") for (int n2 = 0; n2 < 2; ++n2) \
  _Pragma("unroll") for (int ks = 0; ks < 2; ++ks) \
    bfr[(g)*2 + n2][ks] = *(const bf16x8*)&_p[((g)*2 + n2)*1024 + l16*64 + (((ks*4 + quad) ^ sw8) * 8)]; \
} while (0)
#define MM_Q(qm, qn) do { \
  __builtin_amdgcn_s_setprio(1); \
  _Pragma("unroll") for (int m2 = 0; m2 < 4; ++m2) \
  _Pragma("unroll") for (int n2 = 0; n2 < 2; ++n2) \
  _Pragma("unroll") for (int ks = 0; ks < 2; ++ks) \
    acc[(qm)*4 + m2][(qn)*2 + n2] = __builtin_amdgcn_mfma_f32_16x16x32_bf16( \
      af[(qm)*4 + m2][ks], bfr[(qn)*2 + n2][ks], acc[(qm)*4 + m2][(qn)*2 + n2], 0, 0, 0); \
  __builtin_amdgcn_s_setprio(0); \
} while (0)
#define PBAR() do { __builtin_amdgcn_s_barrier(); __builtin_amdgcn_sched_barrier(0); } while (0)
#define WLGK0() do { asm volatile("s_waitcnt lgkmcnt(0)" ::: "memory"); __builtin_amdgcn_sched_barrier(0); } while (0)

__device__ __forceinline__ void gemm256_core(
    const unsigned short* __restrict__ A, const unsigned short* __restrict__ Bt,
    unsigned short* lds, f32x4 acc[8][4], int m0, int n0)
{
  int tid = threadIdx.x;
  int wave = tid >> 6, lane = tid & 63, quad = lane >> 4, l16 = lane & 15;
  int wm = wave >> 2, wn = wave & 3;
  int sw8 = l16 & 7;
  int srow = wave * 8 + (lane >> 3);                   // staging row within a half
  int schk = ((lane & 7) ^ (lane >> 3)) * 8;           // pre-swizzled source chunk
  const unsigned short* Ag = A  + (size_t)(m0 + srow) * 1024 + schk;
  const unsigned short* Bg = Bt + (size_t)(n0 + srow) * 1024 + schk;
  bf16x8 af[8][2], bfr[4][2];

  // prologue: t0 complete; t1 A0,A1,B0 (7 halves = 14 loads in flight)
  STG_A(0, 0, 0); STG_A(0, 0, 1); STG_B(0, 0, 0); STG_B(0, 0, 1);
  STG_A(1, 1, 0); STG_A(1, 1, 1); STG_B(1, 1, 0);
  asm volatile("s_waitcnt vmcnt(6)" ::: "memory");     // t0's 8 loads landed
  PBAR();

  for (int t = 0; t < 16; t += 2) {
    // ---- phase 1: q(0,0) of tile t ----
    RD_AG(0, 0); RD_BG(0, 0);
    STG_B(t + 1, 1, 1);
    __builtin_amdgcn_s_barrier(); WLGK0();
    MM_Q(0, 0);
    PBAR();
    // ---- phase 2: q(1,0) ----
    RD_AG(1, 0);
    __builtin_amdgcn_s_barrier(); WLGK0();
    MM_Q(1, 0);
    PBAR();
    // ---- phase 3: q(0,1) ----
    RD_BG(1, 0);
    if (t + 2 < 16) { STG_A(t + 2, 0, 0); STG_A(t + 2, 0, 1); }
    __builtin_amdgcn_s_barrier(); WLGK0();
    MM_Q(0, 1);
    PBAR();
    // ---- phase 4: q(1,1), gate tile t+1 ----
    if (t + 2 < 16) STG_B(t + 2, 0, 0);
    __builtin_amdgcn_s_barrier(); __builtin_amdgcn_sched_barrier(0);
    MM_Q(1, 1);
    if (t + 2 < 16) { asm volatile("s_waitcnt vmcnt(6)" ::: "memory"); }
    else            { asm volatile("s_waitcnt vmcnt(0)" ::: "memory"); }
    PBAR();
    // ---- phase 5: q(0,0) of tile t+1 ----
    RD_AG(0, 1); RD_BG(0, 1);
    if (t + 2 < 16) STG_B(t + 2, 0, 1);
    __builtin_amdgcn_s_barrier(); WLGK0();
    MM_Q(0, 0);
    PBAR();
    // ---- phase 6: q(1,0) ----
    RD_AG(1, 1);
    __builtin_amdgcn_s_barrier(); WLGK0();
    MM_Q(1, 0);
    PBAR();
    // ---- phase 7: q(0,1) ----
    RD_BG(1, 1);
    if (t + 3 < 16) { STG_A(t + 3, 1, 0); STG_A(t + 3, 1, 1); }
    __builtin_amdgcn_s_barrier(); WLGK0();
    MM_Q(0, 1);
    PBAR();
    // ---- phase 8: q(1,1), gate tile t+2 ----
    if (t + 3 < 16) STG_B(t + 3, 1, 0);
    __builtin_amdgcn_s_barrier(); __builtin_amdgcn_sched_barrier(0);
    MM_Q(1, 1);
    if (t + 3 < 16) { asm volatile("s_waitcnt vmcnt(6)" ::: "memory"); }
    PBAR();
  }
}

// ---------------- 9 projection GEMMs: P[s*3+w] = Xbf[s] @ W[w] + bias[w], bf16 out ----------------
// w==2 (V) is stored TRANSPOSED into its P slice: [(b*16+h)][d][l] (fused transpose_v)
__global__ __launch_bounds__(512, 2) void gemm_proj(
    const unsigned short* __restrict__ Xbf, const unsigned short* __restrict__ Wt,
    unsigned short* __restrict__ P,
    const float* __restrict__ bq, const float* __restrict__ bk, const float* __restrict__ bv)
{
  __shared__ alignas(16) unsigned short lds[65536];    // 128 KiB
  int z = blockIdx.z, s = z / 3, w = z - s * 3;
  const float* bias = (w == 0) ? bq : (w == 1) ? bk : bv;
  int f = blockIdx.x;
  int swz = (f & 7) * 16 + (f >> 3);                   // XCD-aware, 128 wgs/z, bijective
  int m0 = (swz & 31) * 256, n0 = (swz >> 5) * 256;
  f32x4 acc[8][4];
#pragma unroll
  for (int i = 0; i < 8; i++)
#pragma unroll
    for (int j = 0; j < 4; j++) acc[i][j] = (f32x4){0.f, 0.f, 0.f, 0.f};
  gemm256_core(Xbf + (size_t)s * NTOK * 1024, Wt + (size_t)w * 1048576, lds, acc, m0, n0);

  int tid = threadIdx.x, wave = tid >> 6, lane = tid & 63, quad = lane >> 4, l16 = lane & 15;
  int wm = wave >> 2, wn = wave & 3;
  int rbase = m0 + wm * 128, cbase = n0 + wn * 64;
  unsigned short* C = P + (size_t)z * NTOK * 1024;
  if (w == 2) {
    // fused V transpose: lane's 4 consecutive C-rows = consecutive l -> ushort4 store
#pragma unroll
    for (int mi = 0; mi < 8; mi++) {
      int row0 = rbase + mi * 16 + quad * 4;
      int b = row0 >> 10, l0 = row0 & 1023;
#pragma unroll
      for (int ni = 0; ni < 4; ni++) {
        int col = cbase + ni * 16 + l16;
        float bcol = bias[col];
        int hh = col >> 6, d = col & 63;
        ushort4 o4;
        o4.x = f2bf(acc[mi][ni][0] + bcol);
        o4.y = f2bf(acc[mi][ni][1] + bcol);
        o4.z = f2bf(acc[mi][ni][2] + bcol);
        o4.w = f2bf(acc[mi][ni][3] + bcol);
        *(ushort4*)&C[(size_t)(b * 16 + hh) * 65536 + (size_t)d * 1024 + l0] = o4;
      }
    }
  } else {
#pragma unroll
    for (int mi = 0; mi < 8; mi++)
#pragma unroll
      for (int ni = 0; ni < 4; ni++) {
        int col = cbase + ni * 16 + l16;
        float bcol = bias[col];
#pragma unroll
        for (int r = 0; r < 4; r++) {
          int row = rbase + mi * 16 + quad * 4 + r;
          C[(size_t)row * 1024 + col] = f2bf(acc[mi][ni][r] + bcol);
        }
      }
  }
}

// ---------------- output GEMM: d_out[tok][s][:] = Oa[s] @ Wo + bo (fp32) ----------------
__global__ __launch_bounds__(512, 2) void gemm_out(
    const unsigned short* __restrict__ Oattn, const unsigned short* __restrict__ WtO,
    float* __restrict__ out, const float* __restrict__ bo)
{
  __shared__ alignas(16) unsigned short lds[65536];    // 128 KiB
  int s = blockIdx.z;
  int f = blockIdx.x;
  int swz = (f & 7) * 16 + (f >> 3);
  int m0 = (swz & 31) * 256, n0 = (swz >> 5) * 256;
  f32x4 acc[8][4];
#pragma unroll
  for (int i = 0; i < 8; i++)
#pragma unroll
    for (int j = 0; j < 4; j++) acc[i][j] = (f32x4){0.f, 0.f, 0.f, 0.f};
  gemm256_core(Oattn + (size_t)s * NTOK * 1024, WtO, lds, acc, m0, n0);

  int tid = threadIdx.x, wave = tid >> 6, lane = tid & 63, quad = lane >> 4, l16 = lane & 15;
  int wm = wave >> 2, wn = wave & 3;
  int rbase = m0 + wm * 128, cbase = n0 + wn * 64;
#pragma unroll
  for (int mi = 0; mi < 8; mi++)
#pragma unroll
    for (int ni = 0; ni < 4; ni++) {
      int col = cbase + ni * 16 + l16;
      float bcol = bo[col];
#pragma unroll
      for (int r = 0; r < 4; r++) {
        int row = rbase + mi * 16 + quad * 4 + r;
        out[(size_t)row * 3072 + s * 1024 + col] = acc[mi][ni][r] + bcol;
      }
    }
}

// ---------------- fused dual attention v5: grid x=bh (K/V sharers on same XCD), y=q-block ----------------
__global__ __launch_bounds__(256, 4) void attn(
    const unsigned short* __restrict__ P, unsigned short* __restrict__ Oa)
{
  __shared__ alignas(16) unsigned short lK1[64 * 64];   // [key][8 x 16B chunks, XOR-swizzled]
  __shared__ alignas(16) unsigned short lK2[64 * 64];
  __shared__ alignas(16) unsigned short lV [64 * 64];   // [d][8 chunks of keys, XOR-swizzled]
  __shared__ alignas(16) unsigned short pls[4][32 * 40];// per-wave P relayout, 80B rows
  int o  = blockIdx.z;
  int As = (o == 0) ? 1 : 0;          // first (q,k) source stream
  int Bs = (o == 2) ? 1 : 2;          // second (q,k) source stream
  int b = blockIdx.x >> 4, h = blockIdx.x & 15;
  int tid = threadIdx.x, wave = tid >> 6, lane = tid & 63, quad = lane >> 4, l16 = lane & 15;
  int q0 = blockIdx.y * 128 + wave * 32;
  size_t bh_off = (size_t)b * 1024 * 1024 + h * 64;
  const unsigned short* Q1 = P + (size_t)(As * 3 + 0) * NTOK * 1024 + bh_off;
  const unsigned short* K1 = P + (size_t)(As * 3 + 1) * NTOK * 1024 + bh_off;
  const unsigned short* Q2 = P + (size_t)(Bs * 3 + 0) * NTOK * 1024 + bh_off;
  const unsigned short* K2 = P + (size_t)(Bs * 3 + 1) * NTOK * 1024 + bh_off;
  // V lives transposed inside the (o,w==2) P slice: [(b*16+h)][d][l]
  const unsigned short* V  = P + (size_t)(o * 3 + 2) * NTOK * 1024
                               + (size_t)(b * 16 + h) * 65536;
  unsigned short* myp = pls[wave];

  bf16x8 q1f[2][2], q2f[2][2];
#pragma unroll
  for (int qt = 0; qt < 2; qt++)
#pragma unroll
    for (int c = 0; c < 2; c++) {
      q1f[qt][c] = *(const bf16x8*)&Q1[(size_t)(q0 + qt * 16 + l16) * 1024 + c * 32 + quad * 8];
      q2f[qt][c] = *(const bf16x8*)&Q2[(size_t)(q0 + qt * 16 + l16) * 1024 + c * 32 + quad * 8];
    }
  bf16x8 ones;
#pragma unroll
  for (int j = 0; j < 8; j++) ones[j] = (__bf16)1.0f;

  // staging: lane covers row (wave*16 + lane/8), swizzled 16B chunk (lane%8)^(row%8)
  int r8 = lane >> 3;
  int cs = ((lane & 7) ^ r8) * 8;                      // XOR source swizzle
  int srow = wave * 16 + r8;
  const unsigned short* K1s = K1 + (size_t)srow * 1024 + cs;
  const unsigned short* K2s = K2 + (size_t)srow * 1024 + cs;
  const unsigned short* Vs  = V  + (size_t)srow * 1024 + cs;
  int fsw = (l16 & 7);                                 // fragment-read swizzle key

  f32x4 oacc[2][4];
#pragma unroll
  for (int qt = 0; qt < 2; qt++)
#pragma unroll
    for (int dt = 0; dt < 4; dt++) oacc[qt][dt] = (f32x4){0.f, 0.f, 0.f, 0.f};
  f32x4 lsum[2];
  lsum[0] = (f32x4){0.f, 0.f, 0.f, 0.f};
  lsum[1] = (f32x4){0.f, 0.f, 0.f, 0.f};

  const float SC = 0.09016844136867f;  // (1/sqrt(64))*0.5*log2(e)

  for (int k0 = 0; k0 < 1024; k0 += 64) {
#pragma unroll
    for (int half = 0; half < 2; half++) {
      size_t krow = (size_t)(k0 + half * 8) * 1024;
      gld16(K1s + krow,                 lK1 + (wave * 16 + half * 8) * 64);
      gld16(K2s + krow,                 lK2 + (wave * 16 + half * 8) * 64);
      gld16(Vs + k0 + half * 8 * 1024,  lV  + (wave * 16 + half * 8) * 64);
    }
    __syncthreads();

#pragma unroll
    for (int kc = 0; kc < 2; kc++) {              // 32-key halves of the 64-key stage
      f32x4 sacc[2][2];
      sacc[0][0] = (f32x4){0.f, 0.f, 0.f, 0.f};
      sacc[0][1] = (f32x4){0.f, 0.f, 0.f, 0.f};
      sacc[1][0] = (f32x4){0.f, 0.f, 0.f, 0.f};
      sacc[1][1] = (f32x4){0.f, 0.f, 0.f, 0.f};
      __builtin_amdgcn_s_setprio(1);              // T5: favor the QK MFMA cluster
#pragma unroll
      for (int kt = 0; kt < 2; kt++) {
        int krow = (kc * 32 + kt * 16 + l16) * 64;
        bf16x8 k1a = *(const bf16x8*)&lK1[krow + ((quad ^ fsw) * 8)];
        bf16x8 k1b = *(const bf16x8*)&lK1[krow + (((quad + 4) ^ fsw) * 8)];
        bf16x8 k2a = *(const bf16x8*)&lK2[krow + ((quad ^ fsw) * 8)];
        bf16x8 k2b = *(const bf16x8*)&lK2[krow + (((quad + 4) ^ fsw) * 8)];
#pragma unroll
        for (int qt = 0; qt < 2; qt++) {
          sacc[qt][kt] = __builtin_amdgcn_mfma_f32_16x16x32_bf16(q1f[qt][0], k1a, sacc[qt][kt], 0, 0, 0);
          sacc[qt][kt] = __builtin_amdgcn_mfma_f32_16x16x32_bf16(q1f[qt][1], k1b, sacc[qt][kt], 0, 0, 0);
          sacc[qt][kt] = __builtin_amdgcn_mfma_f32_16x16x32_bf16(q2f[qt][0], k2a, sacc[qt][kt], 0, 0, 0);
          sacc[qt][kt] = __builtin_amdgcn_mfma_f32_16x16x32_bf16(q2f[qt][1], k2b, sacc[qt][kt], 0, 0, 0);
        }
      }
      __builtin_amdgcn_s_setprio(0);
      // exp2 -> bf16 pair-pack (round-half-up) -> padded per-wave LDS, read back A-layout
#pragma unroll
      for (int qt = 0; qt < 2; qt++)
#pragma unroll
        for (int kt = 0; kt < 2; kt++)
#pragma unroll
          for (int r2 = 0; r2 < 2; r2++) {
            union { float f; unsigned u; } e0, e1;
            e0.f = __builtin_amdgcn_exp2f(sacc[qt][kt][r2 * 2]     * SC);
            e1.f = __builtin_amdgcn_exp2f(sacc[qt][kt][r2 * 2 + 1] * SC);
            unsigned pk = __builtin_amdgcn_perm(e1.u + 0x8000u, e0.u + 0x8000u, 0x07060302u);
            int row = qt * 16 + quad * 4 + r2 * 2;
            myp[row * 40 + kt * 16 + l16]       = (unsigned short)pk;
            myp[(row + 1) * 40 + kt * 16 + l16] = (unsigned short)(pk >> 16);
          }
      bf16x8 pa0 = *(const bf16x8*)&myp[l16 * 40 + quad * 8];
      bf16x8 pa1 = *(const bf16x8*)&myp[(16 + l16) * 40 + quad * 8];
      __builtin_amdgcn_s_setprio(1);              // T5: favor lsum+PV MFMA cluster
      lsum[0] = __builtin_amdgcn_mfma_f32_16x16x32_bf16(pa0, ones, lsum[0], 0, 0, 0);
      lsum[1] = __builtin_amdgcn_mfma_f32_16x16x32_bf16(pa1, ones, lsum[1], 0, 0, 0);
#pragma unroll
      for (int dt = 0; dt < 4; dt++) {
        bf16x8 vf = *(const bf16x8*)&lV[(dt * 16 + l16) * 64 + (((kc * 4 + quad) ^ fsw) * 8)];
        oacc[0][dt] = __builtin_amdgcn_mfma_f32_16x16x32_bf16(pa0, vf, oacc[0][dt], 0, 0, 0);
        oacc[1][dt] = __builtin_amdgcn_mfma_f32_16x16x32_bf16(pa1, vf, oacc[1][dt], 0, 0, 0);
      }
      __builtin_amdgcn_s_setprio(0);
    }
    __syncthreads();
  }

  unsigned short* Od = Oa + (size_t)o * NTOK * 1024 + bh_off;
#pragma unroll
  for (int qt = 0; qt < 2; qt++) {
    f32x4 inv;
#pragma unroll
    for (int r = 0; r < 4; r++) inv[r] = 1.0f / lsum[qt][r];
#pragma unroll
    for (int dt = 0; dt < 4; dt++)
#pragma unroll
      for (int r = 0; r < 4; r++) {
        float val = oacc[qt][dt][r] * inv[r];
        Od[(size_t)(q0 + qt * 16 + quad * 4 + r) * 1024 + dt * 16 + l16] = f2bf(val);
      }
  }
}

extern "C" void kernel_launch(void* const* d_in, const int* in_sizes, int n_in,
                              void* d_out, int out_size, void* d_ws, size_t ws_size,
                              hipStream_t stream) {
  (void)in_sizes; (void)n_in; (void)out_size; (void)ws_size;
  const float* x  = (const float*)d_in[0];
  const float* Wq = (const float*)d_in[1];
  const float* bq = (const float*)d_in[2];
  const float* Wk = (const float*)d_in[3];
  const float* bk = (const float*)d_in[4];
  const float* Wv = (const float*)d_in[5];
  const float* bv = (const float*)d_in[6];
  const float* Wo = (const float*)d_in[7];
  const float* bo = (const float*)d_in[8];
  float* out = (float*)d_out;

  char* ws = (char*)d_ws;
  // layout (bytes): Xbf 48MB | Wt 8MB | P 144MB (w==2 slices hold Vt-transposed) | Oa 48MB
  unsigned short* Xbf = (unsigned short*)(ws + 0);
  unsigned short* Wt  = (unsigned short*)(ws + 50331648);
  unsigned short* P   = (unsigned short*)(ws + 58720256);
  unsigned short* Oa  = (unsigned short*)(ws + 209715200);

  convert_x<<<24576, 256, 0, stream>>>(x, Xbf);
  dim3 tb(32, 8), tg(32, 32);
  transpose_w<<<tg, tb, 0, stream>>>(Wq, Wt + 0 * 1048576);
  transpose_w<<<tg, tb, 0, stream>>>(Wk, Wt + 1 * 1048576);
  transpose_w<<<tg, tb, 0, stream>>>(Wv, Wt + 2 * 1048576);
  transpose_w<<<tg, tb, 0, stream>>>(Wo, Wt + 3 * 1048576);

  gemm_proj<<<dim3(128, 1, 9), 512, 0, stream>>>(Xbf, Wt, P, bq, bk, bv);
  attn<<<dim3(128, 8, 3), 256, 0, stream>>>(P, Oa);
  gemm_out<<<dim3(128, 1, 3), 512, 0, stream>>>(Oa, Wt + 3 * 1048576, out, bo);
}

// Round 3
// 601.046 us; speedup vs baseline: 1.0219x; 1.0207x over previous
//
#include <hip/hip_runtime.h>
#include <hip/hip_bf16.h>
#include <stdint.h>

#define NTOK 8192          // B*L = 8*1024
#define DM   1024

typedef __bf16 bf16x8 __attribute__((ext_vector_type(8)));
typedef float  f32x4  __attribute__((ext_vector_type(4)));

__device__ __forceinline__ unsigned short f2bf(float f) {
  union { float f; unsigned u; } v; v.f = f;
  unsigned r = v.u + 0x7FFFu + ((v.u >> 16) & 1u);   // round-to-nearest-even
  return (unsigned short)(r >> 16);
}

// async global->LDS, 16B per lane; LDS dest = wave-uniform base + lane*16
__device__ __forceinline__ void gld16(const void* g, const void* l) {
  __builtin_amdgcn_global_load_lds(
      (const __attribute__((address_space(1))) uint32_t*)g,
      (__attribute__((address_space(3))) uint32_t*)l, 16, 0, 0);
}

// ---------------- convert x: fp32 [tok][3][1024] -> bf16 [s][tok][1024] ----------------
__global__ void convert_x(const float* __restrict__ x, unsigned short* __restrict__ Xbf) {
  int idx = (blockIdx.x * 256 + threadIdx.x) * 4;
  int s   = idx >> 23;
  int rem = idx & ((1 << 23) - 1);
  int tok = rem >> 10;
  int d   = rem & 1023;
  const float4 v = *(const float4*)&x[((size_t)tok * 3 + s) * 1024 + d];
  ushort4 o;
  o.x = f2bf(v.x); o.y = f2bf(v.y); o.z = f2bf(v.z); o.w = f2bf(v.w);
  *(ushort4*)&Xbf[idx] = o;
}

// ---------------- W (K x N fp32) -> Wt (N x K bf16), 1024x1024, all 4 in one launch ----------------
__global__ void transpose_w4(const float* __restrict__ W0, const float* __restrict__ W1,
                             const float* __restrict__ W2, const float* __restrict__ W3,
                             unsigned short* __restrict__ Wt) {
  __shared__ float t[32][33];
  int z = blockIdx.z;
  const float* W = (z == 0) ? W0 : (z == 1) ? W1 : (z == 2) ? W2 : W3;
  unsigned short* D = Wt + (size_t)z * 1048576;
  int tx = threadIdx.x, ty = threadIdx.y;            // block (32,8)
  int bx = blockIdx.x * 32, by = blockIdx.y * 32;
#pragma unroll
  for (int i = 0; i < 32; i += 8)
    t[ty + i][tx] = W[(size_t)(by + ty + i) * 1024 + bx + tx];
  __syncthreads();
#pragma unroll
  for (int i = 0; i < 32; i += 8)
    D[(size_t)(bx + ty + i) * 1024 + by + tx] = f2bf(t[tx][ty + i]);  // Wt[n][k]=W[k][n]
}

// ================= 256x256 4-phase/tile GEMM core v2 (T2+T3+T4+T5) =================
// A: Mx1024 bf16 row-major, Bt: Nx1024 bf16 row-major. 512 thr = 8 waves (2M x 4N).
// Per-wave C: 128x64 = 8mi x 4ni frags. K-tile BK=64, double-buffered (2 tiles in LDS).
// LDS 128KB: A slots at 0/32KB, B at 64KB/96KB (slot = t&1). Row = 64 el = 128B = 8 chunks.
// Swizzle: phys chunk p of row r holds logical chunk p^(r&7); staged via pre-swizzled
// global source (gld_lds writes linearly); read with XOR'd chunk (conflict-free b128).
// Phase order Q00,Q01,Q10,Q11 -> af lives only 2 phases (af[4][2], 32 VGPR).
// Staging: Ph1 stages (t+1)B, Ph4 stages (t+2)A; uniform gate vmcnt(4) at Ph4
// (outstanding: t+1 A+B = 8 oldest drained, t+2 A = 4 left). Peak 12 in flight.
// WAR: (t+2)A overwrites t's A-slot, staged after Ph3's post-barrier (last A read).
//      (t+1)B overwrites (t-1)'s B-slot, last read Ph2 of t-1 (3 barriers earlier).
#define STGA(tt) do { _Pragma("unroll") for (int j = 0; j < 4; ++j) \
  gld16(Ag + (size_t)(j * 64) * 1024 + (tt) * 64, &lds[(((tt) & 1) * 16384) + j * 4096 + wave * 512]); } while (0)
#define STGB(tt) do { _Pragma("unroll") for (int j = 0; j < 4; ++j) \
  gld16(Bg + (size_t)(j * 64) * 1024 + (tt) * 64, &lds[32768 + (((tt) & 1) * 16384) + j * 4096 + wave * 512]); } while (0)
#define RDAF(g, tt) do { \
  const unsigned short* _p = &lds[(((tt) & 1) * 16384) + (wm * 128 + (g) * 64) * 64]; \
  _Pragma("unroll") for (int m2 = 0; m2 < 4; ++m2) \
  _Pragma("unroll") for (int ks = 0; ks < 2; ++ks) \
    af[m2][ks] = *(const bf16x8*)&_p[(m2 * 16 + l16) * 64 + (((ks * 4 + quad) ^ sw8) * 8)]; } while (0)
#define RDBF(h, tt) do { \
  const unsigned short* _p = &lds[32768 + (((tt) & 1) * 16384) + (wn * 64 + (h) * 32) * 64]; \
  _Pragma("unroll") for (int n2 = 0; n2 < 2; ++n2) \
  _Pragma("unroll") for (int ks = 0; ks < 2; ++ks) \
    bfr[(h) * 2 + n2][ks] = *(const bf16x8*)&_p[(n2 * 16 + l16) * 64 + (((ks * 4 + quad) ^ sw8) * 8)]; } while (0)
#define MMQ(g, h) do { __builtin_amdgcn_s_setprio(1); \
  _Pragma("unroll") for (int m2 = 0; m2 < 4; ++m2) \
  _Pragma("unroll") for (int n2 = 0; n2 < 2; ++n2) \
  _Pragma("unroll") for (int ks = 0; ks < 2; ++ks) \
    acc[(g) * 4 + m2][(h) * 2 + n2] = __builtin_amdgcn_mfma_f32_16x16x32_bf16( \
      af[m2][ks], bfr[(h) * 2 + n2][ks], acc[(g) * 4 + m2][(h) * 2 + n2], 0, 0, 0); \
  __builtin_amdgcn_s_setprio(0); } while (0)

__device__ __forceinline__ void gemm256_core(
    const unsigned short* __restrict__ A, const unsigned short* __restrict__ Bt,
    unsigned short* lds, f32x4 acc[8][4], int m0, int n0)
{
  int tid = threadIdx.x;
  int wave = tid >> 6, lane = tid & 63, quad = lane >> 4, l16 = lane & 15;
  int wm = wave >> 2, wn = wave & 3;
  int sw8 = l16 & 7;
  int srow = wave * 8 + (lane >> 3);                   // staging row within a 64-row unit
  int schk = ((lane & 7) ^ (lane >> 3)) * 8;           // pre-swizzled source chunk
  const unsigned short* Ag = A  + (size_t)(m0 + srow) * 1024 + schk;
  const unsigned short* Bg = Bt + (size_t)(n0 + srow) * 1024 + schk;
  bf16x8 af[4][2], bfr[4][2];

  // prologue: t0 A+B, t1 A  (12 loads in flight) -> drain t0, keep t1A
  STGA(0); STGB(0); STGA(1);
  asm volatile("s_waitcnt vmcnt(4)" ::: "memory");
  __builtin_amdgcn_s_barrier();
  __builtin_amdgcn_sched_barrier(0);

  for (int t = 0; t < 16; ++t) {
    // ---- phase 1: Q(0,0) ----
    RDAF(0, t); RDBF(0, t);
    if (t + 1 < 16) STGB(t + 1);
    __builtin_amdgcn_s_barrier();
    MMQ(0, 0);
    __builtin_amdgcn_s_barrier();
    // ---- phase 2: Q(0,1) ----
    RDBF(1, t);
    __builtin_amdgcn_s_barrier();
    MMQ(0, 1);
    __builtin_amdgcn_s_barrier();
    // ---- phase 3: Q(1,0) ----
    RDAF(1, t);
    __builtin_amdgcn_s_barrier();
    MMQ(1, 0);
    __builtin_amdgcn_s_barrier();
    // ---- phase 4: Q(1,1) + stage (t+2)A + gate tile t+1 ----
    if (t + 2 < 16) STGA(t + 2);
    __builtin_amdgcn_s_barrier();
    MMQ(1, 1);
    if (t + 2 < 16)      { asm volatile("s_waitcnt vmcnt(4)" ::: "memory"); }
    else if (t == 14)    { asm volatile("s_waitcnt vmcnt(0)" ::: "memory"); }
    __builtin_amdgcn_s_barrier();
    __builtin_amdgcn_sched_barrier(0);
  }
}

// ---------------- 9 projection GEMMs: P[s*3+w] = Xbf[s] @ W[w] + bias[w], bf16 out ----------------
// w==0 (Q) is pre-scaled by SC = (1/sqrt(64))*0.5*log2(e) so attn's exp2 needs no mul.
// w==2 (V) is stored TRANSPOSED into its P slice: [(b*16+h)][d][l] (fused transpose_v)
__global__ __launch_bounds__(512, 2) void gemm_proj(
    const unsigned short* __restrict__ Xbf, const unsigned short* __restrict__ Wt,
    unsigned short* __restrict__ P,
    const float* __restrict__ bq, const float* __restrict__ bk, const float* __restrict__ bv)
{
  __shared__ alignas(16) unsigned short lds[65536];    // 128 KiB
  int z = blockIdx.z, s = z / 3, w = z - s * 3;
  const float* bias = (w == 0) ? bq : (w == 1) ? bk : bv;
  float osc = (w == 0) ? 0.09016844136867f : 1.0f;     // Q pre-scale
  int f = blockIdx.x;
  int swz = (f & 7) * 16 + (f >> 3);                   // XCD-aware, 128 wgs/z, bijective
  int m0 = (swz & 31) * 256, n0 = (swz >> 5) * 256;
  f32x4 acc[8][4];
#pragma unroll
  for (int i = 0; i < 8; i++)
#pragma unroll
    for (int j = 0; j < 4; j++) acc[i][j] = (f32x4){0.f, 0.f, 0.f, 0.f};
  gemm256_core(Xbf + (size_t)s * NTOK * 1024, Wt + (size_t)w * 1048576, lds, acc, m0, n0);

  int tid = threadIdx.x, wave = tid >> 6, lane = tid & 63, quad = lane >> 4, l16 = lane & 15;
  int wm = wave >> 2, wn = wave & 3;
  int rbase = m0 + wm * 128, cbase = n0 + wn * 64;
  unsigned short* C = P + (size_t)z * NTOK * 1024;
  if (w == 2) {
    // fused V transpose: lane's 4 consecutive C-rows = consecutive l -> ushort4 store
#pragma unroll
    for (int mi = 0; mi < 8; mi++) {
      int row0 = rbase + mi * 16 + quad * 4;
      int b = row0 >> 10, l0 = row0 & 1023;
#pragma unroll
      for (int ni = 0; ni < 4; ni++) {
        int col = cbase + ni * 16 + l16;
        float bcol = bias[col];
        int hh = col >> 6, d = col & 63;
        ushort4 o4;
        o4.x = f2bf(acc[mi][ni][0] + bcol);
        o4.y = f2bf(acc[mi][ni][1] + bcol);
        o4.z = f2bf(acc[mi][ni][2] + bcol);
        o4.w = f2bf(acc[mi][ni][3] + bcol);
        *(ushort4*)&C[(size_t)(b * 16 + hh) * 65536 + (size_t)d * 1024 + l0] = o4;
      }
    }
  } else {
#pragma unroll
    for (int mi = 0; mi < 8; mi++)
#pragma unroll
      for (int ni = 0; ni < 4; ni++) {
        int col = cbase + ni * 16 + l16;
        float bcol = bias[col];
#pragma unroll
        for (int r = 0; r < 4; r++) {
          int row = rbase + mi * 16 + quad * 4 + r;
          C[(size_t)row * 1024 + col] = f2bf((acc[mi][ni][r] + bcol) * osc);
        }
      }
  }
}

// ---------------- output GEMM: d_out[tok][s][:] = Oa[s] @ Wo + bo (fp32) ----------------
__global__ __launch_bounds__(512, 2) void gemm_out(
    const unsigned short* __restrict__ Oattn, const unsigned short* __restrict__ WtO,
    float* __restrict__ out, const float* __restrict__ bo)
{
  __shared__ alignas(16) unsigned short lds[65536];    // 128 KiB
  int s = blockIdx.z;
  int f = blockIdx.x;
  int swz = (f & 7) * 16 + (f >> 3);
  int m0 = (swz & 31) * 256, n0 = (swz >> 5) * 256;
  f32x4 acc[8][4];
#pragma unroll
  for (int i = 0; i < 8; i++)
#pragma unroll
    for (int j = 0; j < 4; j++) acc[i][j] = (f32x4){0.f, 0.f, 0.f, 0.f};
  gemm256_core(Oattn + (size_t)s * NTOK * 1024, WtO, lds, acc, m0, n0);

  int tid = threadIdx.x, wave = tid >> 6, lane = tid & 63, quad = lane >> 4, l16 = lane & 15;
  int wm = wave >> 2, wn = wave & 3;
  int rbase = m0 + wm * 128, cbase = n0 + wn * 64;
#pragma unroll
  for (int mi = 0; mi < 8; mi++)
#pragma unroll
    for (int ni = 0; ni < 4; ni++) {
      int col = cbase + ni * 16 + l16;
      float bcol = bo[col];
#pragma unroll
      for (int r = 0; r < 4; r++) {
        int row = rbase + mi * 16 + quad * 4 + r;
        out[(size_t)row * 3072 + s * 1024 + col] = acc[mi][ni][r] + bcol;
      }
    }
}

// ---------------- fused dual attention: grid x=bh (K/V sharers on same XCD), y=q-block ----------------
// Q slices are pre-scaled by SC at projection time -> exp2 takes sacc directly.
__global__ __launch_bounds__(256, 4) void attn(
    const unsigned short* __restrict__ P, unsigned short* __restrict__ Oa)
{
  __shared__ alignas(16) unsigned short lK1[64 * 64];   // [key][8 x 16B chunks, XOR-swizzled]
  __shared__ alignas(16) unsigned short lK2[64 * 64];
  __shared__ alignas(16) unsigned short lV [64 * 64];   // [d][8 chunks of keys, XOR-swizzled]
  __shared__ alignas(16) unsigned short pls[4][32 * 40];// per-wave P relayout, 80B rows
  int o  = blockIdx.z;
  int As = (o == 0) ? 1 : 0;          // first (q,k) source stream
  int Bs = (o == 2) ? 1 : 2;          // second (q,k) source stream
  int b = blockIdx.x >> 4, h = blockIdx.x & 15;
  int tid = threadIdx.x, wave = tid >> 6, lane = tid & 63, quad = lane >> 4, l16 = lane & 15;
  int q0 = blockIdx.y * 128 + wave * 32;
  size_t bh_off = (size_t)b * 1024 * 1024 + h * 64;
  const unsigned short* Q1 = P + (size_t)(As * 3 + 0) * NTOK * 1024 + bh_off;
  const unsigned short* K1 = P + (size_t)(As * 3 + 1) * NTOK * 1024 + bh_off;
  const unsigned short* Q2 = P + (size_t)(Bs * 3 + 0) * NTOK * 1024 + bh_off;
  const unsigned short* K2 = P + (size_t)(Bs * 3 + 1) * NTOK * 1024 + bh_off;
  // V lives transposed inside the (o,w==2) P slice: [(b*16+h)][d][l]
  const unsigned short* V  = P + (size_t)(o * 3 + 2) * NTOK * 1024
                               + (size_t)(b * 16 + h) * 65536;
  unsigned short* myp = pls[wave];

  bf16x8 q1f[2][2], q2f[2][2];
#pragma unroll
  for (int qt = 0; qt < 2; qt++)
#pragma unroll
    for (int c = 0; c < 2; c++) {
      q1f[qt][c] = *(const bf16x8*)&Q1[(size_t)(q0 + qt * 16 + l16) * 1024 + c * 32 + quad * 8];
      q2f[qt][c] = *(const bf16x8*)&Q2[(size_t)(q0 + qt * 16 + l16) * 1024 + c * 32 + quad * 8];
    }
  bf16x8 ones;
#pragma unroll
  for (int j = 0; j < 8; j++) ones[j] = (__bf16)1.0f;

  // staging: lane covers row (wave*16 + lane/8), swizzled 16B chunk (lane%8)^(row%8)
  int r8 = lane >> 3;
  int cs = ((lane & 7) ^ r8) * 8;                      // XOR source swizzle
  int srow = wave * 16 + r8;
  const unsigned short* K1s = K1 + (size_t)srow * 1024 + cs;
  const unsigned short* K2s = K2 + (size_t)srow * 1024 + cs;
  const unsigned short* Vs  = V  + (size_t)srow * 1024 + cs;
  int fsw = (l16 & 7);                                 // fragment-read swizzle key

  f32x4 oacc[2][4];
#pragma unroll
  for (int qt = 0; qt < 2; qt++)
#pragma unroll
    for (int dt = 0; dt < 4; dt++) oacc[qt][dt] = (f32x4){0.f, 0.f, 0.f, 0.f};
  f32x4 lsum[2];
  lsum[0] = (f32x4){0.f, 0.f, 0.f, 0.f};
  lsum[1] = (f32x4){0.f, 0.f, 0.f, 0.f};

  for (int k0 = 0; k0 < 1024; k0 += 64) {
#pragma unroll
    for (int half = 0; half < 2; half++) {
      size_t krow = (size_t)(k0 + half * 8) * 1024;
      gld16(K1s + krow,                 lK1 + (wave * 16 + half * 8) * 64);
      gld16(K2s + krow,                 lK2 + (wave * 16 + half * 8) * 64);
      gld16(Vs + k0 + half * 8 * 1024,  lV  + (wave * 16 + half * 8) * 64);
    }
    __syncthreads();

#pragma unroll
    for (int kc = 0; kc < 2; kc++) {              // 32-key halves of the 64-key stage
      f32x4 sacc[2][2];
      sacc[0][0] = (f32x4){0.f, 0.f, 0.f, 0.f};
      sacc[0][1] = (f32x4){0.f, 0.f, 0.f, 0.f};
      sacc[1][0] = (f32x4){0.f, 0.f, 0.f, 0.f};
      sacc[1][1] = (f32x4){0.f, 0.f, 0.f, 0.f};
      __builtin_amdgcn_s_setprio(1);              // T5: favor the QK MFMA cluster
#pragma unroll
      for (int kt = 0; kt < 2; kt++) {
        int krow = (kc * 32 + kt * 16 + l16) * 64;
        bf16x8 k1a = *(const bf16x8*)&lK1[krow + ((quad ^ fsw) * 8)];
        bf16x8 k1b = *(const bf16x8*)&lK1[krow + (((quad + 4) ^ fsw) * 8)];
        bf16x8 k2a = *(const bf16x8*)&lK2[krow + ((quad ^ fsw) * 8)];
        bf16x8 k2b = *(const bf16x8*)&lK2[krow + (((quad + 4) ^ fsw) * 8)];
#pragma unroll
        for (int qt = 0; qt < 2; qt++) {
          sacc[qt][kt] = __builtin_amdgcn_mfma_f32_16x16x32_bf16(q1f[qt][0], k1a, sacc[qt][kt], 0, 0, 0);
          sacc[qt][kt] = __builtin_amdgcn_mfma_f32_16x16x32_bf16(q1f[qt][1], k1b, sacc[qt][kt], 0, 0, 0);
          sacc[qt][kt] = __builtin_amdgcn_mfma_f32_16x16x32_bf16(q2f[qt][0], k2a, sacc[qt][kt], 0, 0, 0);
          sacc[qt][kt] = __builtin_amdgcn_mfma_f32_16x16x32_bf16(q2f[qt][1], k2b, sacc[qt][kt], 0, 0, 0);
        }
      }
      __builtin_amdgcn_s_setprio(0);
      // exp2 -> bf16 pair-pack (round-half-up) -> padded per-wave LDS, read back A-layout
#pragma unroll
      for (int qt = 0; qt < 2; qt++)
#pragma unroll
        for (int kt = 0; kt < 2; kt++)
#pragma unroll
          for (int r2 = 0; r2 < 2; r2++) {
            union { float f; unsigned u; } e0, e1;
            e0.f = __builtin_amdgcn_exp2f(sacc[qt][kt][r2 * 2]);
            e1.f = __builtin_amdgcn_exp2f(sacc[qt][kt][r2 * 2 + 1]);
            unsigned pk = __builtin_amdgcn_perm(e1.u + 0x8000u, e0.u + 0x8000u, 0x07060302u);
            int row = qt * 16 + quad * 4 + r2 * 2;
            myp[row * 40 + kt * 16 + l16]       = (unsigned short)pk;
            myp[(row + 1) * 40 + kt * 16 + l16] = (unsigned short)(pk >> 16);
          }
      bf16x8 pa0 = *(const bf16x8*)&myp[l16 * 40 + quad * 8];
      bf16x8 pa1 = *(const bf16x8*)&myp[(16 + l16) * 40 + quad * 8];
      __builtin_amdgcn_s_setprio(1);              // T5: favor lsum+PV MFMA cluster
      lsum[0] = __builtin_amdgcn_mfma_f32_16x16x32_bf16(pa0, ones, lsum[0], 0, 0, 0);
      lsum[1] = __builtin_amdgcn_mfma_f32_16x16x32_bf16(pa1, ones, lsum[1], 0, 0, 0);
#pragma unroll
      for (int dt = 0; dt < 4; dt++) {
        bf16x8 vf = *(const bf16x8*)&lV[(dt * 16 + l16) * 64 + (((kc * 4 + quad) ^ fsw) * 8)];
        oacc[0][dt] = __builtin_amdgcn_mfma_f32_16x16x32_bf16(pa0, vf, oacc[0][dt], 0, 0, 0);
        oacc[1][dt] = __builtin_amdgcn_mfma_f32_16x16x32_bf16(pa1, vf, oacc[1][dt], 0, 0, 0);
      }
      __builtin_amdgcn_s_setprio(0);
    }
    __syncthreads();
  }

  unsigned short* Od = Oa + (size_t)o * NTOK * 1024 + bh_off;
#pragma unroll
  for (int qt = 0; qt < 2; qt++) {
    f32x4 inv;
#pragma unroll
    for (int r = 0; r < 4; r++) inv[r] = 1.0f / lsum[qt][r];
#pragma unroll
    for (int dt = 0; dt < 4; dt++)
#pragma unroll
      for (int r = 0; r < 4; r++) {
        float val = oacc[qt][dt][r] * inv[r];
        Od[(size_t)(q0 + qt * 16 + quad * 4 + r) * 1024 + dt * 16 + l16] = f2bf(val);
      }
  }
}

extern "C" void kernel_launch(void* const* d_in, const int* in_sizes, int n_in,
                              void* d_out, int out_size, void* d_ws, size_t ws_size,
                              hipStream_t stream) {
  (void)in_sizes; (void)n_in; (void)out_size; (void)ws_size;
  const float* x  = (const float*)d_in[0];
  const float* Wq = (const float*)d_in[1];
  const float* bq = (const float*)d_in[2];
  const float* Wk = (const float*)d_in[3];
  const float* bk = (const float*)d_in[4];
  const float* Wv = (const float*)d_in[5];
  const float* bv = (const float*)d_in[6];
  const float* Wo = (const float*)d_in[7];
  const float* bo = (const float*)d_in[8];
  float* out = (float*)d_out;

  char* ws = (char*)d_ws;
  // layout (bytes): Xbf 48MB | Wt 8MB | P 144MB (w==2 slices hold Vt-transposed) | Oa 48MB
  unsigned short* Xbf = (unsigned short*)(ws + 0);
  unsigned short* Wt  = (unsigned short*)(ws + 50331648);
  unsigned short* P   = (unsigned short*)(ws + 58720256);
  unsigned short* Oa  = (unsigned short*)(ws + 209715200);

  convert_x<<<24576, 256, 0, stream>>>(x, Xbf);
  transpose_w4<<<dim3(32, 32, 4), dim3(32, 8), 0, stream>>>(Wq, Wk, Wv, Wo, Wt);

  gemm_proj<<<dim3(128, 1, 9), 512, 0, stream>>>(Xbf, Wt, P, bq, bk, bv);
  attn<<<dim3(128, 8, 3), 256, 0, stream>>>(P, Oa);
  gemm_out<<<dim3(128, 1, 3), 512, 0, stream>>>(Oa, Wt + 3 * 1048576, out, bo);
}